// Round 6
// baseline (243.729 us; speedup 1.0000x reference)
//
#include <hip/hip_runtime.h>
#include <hip/hip_bf16.h>

#define NROWS   262144
#define DIN     480
#define DOUT    480

#define M_TILE  32
#define XSTR    488   // ushort stride; 976B/row, 16B-aligned rows, 2-way-bank b128 reads

#define CST_SILU 1.6765290f
#define CST_RELU 1.4142135623730951f
#define INV_S128 0.08838834764831845f
#define INV_S64  0.125f
#define INV_S32  0.17677669529663687f

// ws fragment layout (bf16x8 per lane, 1024B per fragment):
//   W0 tile t(0..13) kk(0..3) -> t*4+kk (0..55); W1 vu,kk -> 56+vu*2+kk; W2 tu -> 64+tu
#define WS_FRAGS 66
#define WS_BYTES (WS_FRAGS * 64 * 16)

typedef short bf16x8 __attribute__((ext_vector_type(8)));
typedef float f32x4  __attribute__((ext_vector_type(4)));

__device__ __forceinline__ ushort f2bf(float f) {
    unsigned u = __float_as_uint(f);
    u = (u + 0x7FFFu + ((u >> 16) & 1u)) >> 16;   // RNE
    return (ushort)u;
}

// packed f32 pair -> 2x bf16 in one u32 (v_cvt_pk_bf16_f32)
__device__ __forceinline__ unsigned pk2(float a, float b) {
    __hip_bfloat162 h = __float22bfloat162_rn(float2{a, b});
    return *reinterpret_cast<unsigned*>(&h);
}

__device__ __forceinline__ bf16x8 load_b_frag(const float* __restrict__ W, int ldw,
                                              int kbase, int nbase, int lane) {
    int n  = nbase + (lane & 15);
    int k0 = kbase + ((lane >> 4) << 3);
    bf16x8 f;
#pragma unroll
    for (int e = 0; e < 8; ++e) f[e] = (short)f2bf(W[(k0 + e) * ldw + n]);
    return f;
}

__global__ __launch_bounds__(64) void prep_frags(
        const float* __restrict__ W0, const float* __restrict__ W1,
        const float* __restrict__ W2, ushort* __restrict__ ws) {
    const int b = blockIdx.x, lane = threadIdx.x;
    const int lr = lane & 15, kg = lane >> 4;
    const float* W; int ldw, n, k0;
    if (b < 56)      { W = W0; ldw = 224; n = (b >> 2) * 16 + lr; k0 = (b & 3) * 32 + (kg << 3); }
    else if (b < 64) { int t = b - 56; W = W1; ldw = 64; n = (t >> 1) * 16 + lr; k0 = (t & 1) * 32 + (kg << 3); }
    else             { W = W2; ldw = 32; n = (b - 64) * 16 + lr; k0 = (kg << 3); }
    bf16x8 f;
#pragma unroll
    for (int e = 0; e < 8; ++e) f[e] = (short)f2bf(W[(k0 + e) * ldw + n]);
    *reinterpret_cast<bf16x8*>(ws + (b * 64 + lane) * 8) = f;
}

template <bool PRE>
__global__ __launch_bounds__(256, 5) void percep_kernel(   // 5: 102-reg cap fits the slim live set; 20 waves/CU
        const float* __restrict__ x,  const float* __restrict__ W0,
        const float* __restrict__ bias0, const float* __restrict__ W1,
        const float* __restrict__ W2, float* __restrict__ out,
        const ushort* __restrict__ ws) {
    __shared__ __align__(16) ushort xs[M_TILE * XSTR];   // 31232 B -> 5 blocks/CU

    const int tid  = threadIdx.x;
    const int lane = tid & 63;
    const int wid  = tid >> 6;
    const int lr   = lane & 15;
    const int kg   = lane >> 4;
    const int rf   = wid >> 1;      // row-panel: waves 0,1 -> rows 0-15; 2,3 -> 16-31
    const int half = wid & 1;       // column-half of the S/V/T work
    const int row0 = blockIdx.x * M_TILE;
    const bf16x8* F = reinterpret_cast<const bf16x8*>(ws);

    // ---------- stage all of x -> LDS bf16 (coalesced float4, packed cvt) ----------
    // x0: cols 0..127 straight ; x1[n,i,m]=x[n,128+3i+m] -> col 128+64m+i ;
    // x2[n,i,m]=x[n,320+5i+m] -> col 320+32m+i
#pragma unroll
    for (int it = 0; it < 4; ++it) {
        int idx = tid + it * 256;
        int row = idx >> 5, c4 = idx & 31;
        const float4 v = reinterpret_cast<const float4*>(x + (row0 + row) * DIN)[c4];
        uint2 o = { pk2(v.x, v.y), pk2(v.z, v.w) };
        *reinterpret_cast<uint2*>(&xs[row * XSTR + c4 * 4]) = o;
    }
#pragma unroll
    for (int it = 0; it < 2; ++it) {
        int idx = tid + it * 256;
        int row = idx >> 4, g = idx & 15;
        const float4* p = reinterpret_cast<const float4*>(x + (row0 + row) * DIN + 128 + 12 * g);
        float4 q0 = p[0], q1 = p[1], q2 = p[2];
        float v[12] = { q0.x, q0.y, q0.z, q0.w, q1.x, q1.y, q1.z, q1.w, q2.x, q2.y, q2.z, q2.w };
#pragma unroll
        for (int m = 0; m < 3; ++m) {
            uint2 o = { pk2(v[m], v[m + 3]), pk2(v[m + 6], v[m + 9]) };
            *reinterpret_cast<uint2*>(&xs[row * XSTR + 128 + 64 * m + 4 * g]) = o;
        }
    }
    {
        int row = tid >> 3, g = tid & 7;
        const float4* p = reinterpret_cast<const float4*>(x + (row0 + row) * DIN + 320 + 20 * g);
        float4 q0 = p[0], q1 = p[1], q2 = p[2], q3 = p[3], q4 = p[4];
        float v[20] = { q0.x, q0.y, q0.z, q0.w, q1.x, q1.y, q1.z, q1.w, q2.x, q2.y, q2.z, q2.w,
                        q3.x, q3.y, q3.z, q3.w, q4.x, q4.y, q4.z, q4.w };
#pragma unroll
        for (int m = 0; m < 5; ++m) {
            uint2 o = { pk2(v[m], v[m + 5]), pk2(v[m + 10], v[m + 15]) };
            *reinterpret_cast<uint2*>(&xs[row * XSTR + 320 + 32 * m + 4 * g]) = o;
        }
    }
    __syncthreads();   // the only barrier

    // ---------- A-frags for S (own row panel, from LDS) ----------
    bf16x8 aS[4];
#pragma unroll
    for (int kk = 0; kk < 4; ++kk)
        aS[kk] = *reinterpret_cast<const bf16x8*>(
            &xs[(rf * 16 + lr) * XSTR + kk * 32 + (kg << 3)]);

    const int orow = row0 + rf * 16 + (kg << 2);   // first of this thread's 4 output rows

    auto s_acc = [&](int st) -> f32x4 {
        f32x4 acc = { 0.f, 0.f, 0.f, 0.f };
#pragma unroll
        for (int kk = 0; kk < 4; ++kk) {
            bf16x8 b = PRE ? F[(st * 4 + kk) * 64 + lane]
                           : load_b_frag(W0, 224, kk * 32, st * 16, lane);
            acc = __builtin_amdgcn_mfma_f32_16x16x32_bf16(aS[kk], b, acc, 0, 0, 0);
        }
        return acc;
    };
    auto gate_tile = [&](int st) -> f32x4 {
        f32x4 acc = s_acc(st);
        float bias = bias0[st * 16 + lr];
        f32x4 g;
#pragma unroll
        for (int r = 0; r < 4; ++r) {
            float s = acc[r] * INV_S128 + bias;
            g[r] = fmaxf(s, 0.f) * CST_RELU;
        }
        return g;
    };
    auto silu_tile = [&](int st) {
        f32x4 acc = s_acc(st);
        float bias = bias0[st * 16 + lr];
#pragma unroll
        for (int r = 0; r < 4; ++r) {
            float s = acc[r] * INV_S128 + bias;
            float val = CST_SILU * s * __builtin_amdgcn_rcpf(1.f + __expf(-s));
            out[(orow + r) * DOUT + st * 16 + lr] = val;
        }
    };
    // V j-tile jtg, gated by g (one live gate at a time); A-frags read inline from LDS
    auto v_tile = [&](int jtg, f32x4 g) {
        f32x4 a0 = {0,0,0,0}, a1 = {0,0,0,0}, a2 = {0,0,0,0};
#pragma unroll
        for (int kk = 0; kk < 2; ++kk) {
            bf16x8 b = PRE ? F[(56 + jtg * 2 + kk) * 64 + lane]
                           : load_b_frag(W1, 64, kk * 32, jtg * 16, lane);
            const ushort* base = &xs[(rf * 16 + lr) * XSTR + 128 + kk * 32 + (kg << 3)];
            a0 = __builtin_amdgcn_mfma_f32_16x16x32_bf16(*reinterpret_cast<const bf16x8*>(base +   0), b, a0, 0, 0, 0);
            a1 = __builtin_amdgcn_mfma_f32_16x16x32_bf16(*reinterpret_cast<const bf16x8*>(base +  64), b, a1, 0, 0, 0);
            a2 = __builtin_amdgcn_mfma_f32_16x16x32_bf16(*reinterpret_cast<const bf16x8*>(base + 128), b, a2, 0, 0, 0);
        }
        int j = jtg * 16 + lr;
#pragma unroll
        for (int r = 0; r < 4; ++r) {
            float gg = g[r] * INV_S64;
            float* po = out + (orow + r) * DOUT + 128 + 3 * j;
            po[0] = a0[r] * gg; po[1] = a1[r] * gg; po[2] = a2[r] * gg;
        }
    };
    auto t_tile = [&](int tu, f32x4 g) {
        bf16x8 bt = PRE ? F[(64 + tu) * 64 + lane]
                        : load_b_frag(W2, 32, 0, tu * 16, lane);
        const ushort* base = &xs[(rf * 16 + lr) * XSTR + 320 + (kg << 3)];
        f32x4 z = {0,0,0,0};
        f32x4 a0 = __builtin_amdgcn_mfma_f32_16x16x32_bf16(*reinterpret_cast<const bf16x8*>(base +   0), bt, z, 0, 0, 0);
        f32x4 a1 = __builtin_amdgcn_mfma_f32_16x16x32_bf16(*reinterpret_cast<const bf16x8*>(base +  32), bt, z, 0, 0, 0);
        f32x4 a2 = __builtin_amdgcn_mfma_f32_16x16x32_bf16(*reinterpret_cast<const bf16x8*>(base +  64), bt, z, 0, 0, 0);
        f32x4 a3 = __builtin_amdgcn_mfma_f32_16x16x32_bf16(*reinterpret_cast<const bf16x8*>(base +  96), bt, z, 0, 0, 0);
        f32x4 a4 = __builtin_amdgcn_mfma_f32_16x16x32_bf16(*reinterpret_cast<const bf16x8*>(base + 128), bt, z, 0, 0, 0);
        int j = tu * 16 + lr;
#pragma unroll
        for (int r = 0; r < 4; ++r) {
            float gg = g[r] * INV_S32;
            float* po = out + (orow + r) * DOUT + 320 + 5 * j;
            po[0] = a0[r] * gg; po[1] = a1[r] * gg; po[2] = a2[r] * gg;
            po[3] = a3[r] * gg; po[4] = a4[r] * gg;
        }
    };

    // ---------- interleaved schedule: gate -> its consumer, silu spread between ----------
    const int gt0 = half ? 10 : 8, gt1 = half ? 11 : 9, gt2 = half ? 13 : 12;
    {
        f32x4 g0 = gate_tile(gt0);
        v_tile(half * 2 + 0, g0);
    }
    silu_tile(half * 4 + 0);
    {
        f32x4 g1 = gate_tile(gt1);
        v_tile(half * 2 + 1, g1);
    }
    silu_tile(half * 4 + 1);
    {
        f32x4 g2 = gate_tile(gt2);
        t_tile(half, g2);
    }
    silu_tile(half * 4 + 2);
    silu_tile(half * 4 + 3);
}

extern "C" void kernel_launch(void* const* d_in, const int* in_sizes, int n_in,
                              void* d_out, int out_size, void* d_ws, size_t ws_size,
                              hipStream_t stream) {
    const float* x  = (const float*)d_in[0];
    const float* W0 = (const float*)d_in[1];
    const float* b0 = (const float*)d_in[2];
    const float* W1 = (const float*)d_in[3];
    const float* W2 = (const float*)d_in[4];
    float* out = (float*)d_out;
    dim3 grid(NROWS / M_TILE), block(256);
    if (ws_size >= WS_BYTES) {
        hipLaunchKernelGGL(prep_frags, dim3(WS_FRAGS), dim3(64), 0, stream, W0, W1, W2, (ushort*)d_ws);
        hipLaunchKernelGGL((percep_kernel<true>), grid, block, 0, stream,
                           x, W0, b0, W1, W2, out, (const ushort*)d_ws);
    } else {
        hipLaunchKernelGGL((percep_kernel<false>), grid, block, 0, stream,
                           x, W0, b0, W1, W2, out, (const ushort*)d_ws);
    }
}

// Round 7
// 236.734 us; speedup vs baseline: 1.0295x; 1.0295x over previous
//
#include <hip/hip_runtime.h>
#include <hip/hip_bf16.h>

#define NROWS   262144
#define DIN     480
#define DOUT    480

#define M_TILE  16
#define XSTR    488   // ushort stride; 976B/row, 16B-aligned rows, 2-way-bank b128 reads

#define CST_SILU 1.6765290f
#define CST_RELU 1.4142135623730951f
#define INV_S128 0.08838834764831845f
#define INV_S64  0.125f
#define INV_S32  0.17677669529663687f

// ws fragment layout (bf16x8 per lane, 1024B per fragment):
//   W0 tile t(0..13) kk(0..3) -> t*4+kk (0..55); W1 jt,kk -> 56+jt*2+kk; W2 tu -> 64+tu
#define WS_FRAGS 66
#define WS_BYTES (WS_FRAGS * 64 * 16)

typedef short bf16x8 __attribute__((ext_vector_type(8)));
typedef float f32x4  __attribute__((ext_vector_type(4)));

__device__ __forceinline__ ushort f2bf(float f) {
    unsigned u = __float_as_uint(f);
    u = (u + 0x7FFFu + ((u >> 16) & 1u)) >> 16;   // RNE
    return (ushort)u;
}

// packed f32 pair -> 2x bf16 in one u32 (v_cvt_pk_bf16_f32)
__device__ __forceinline__ unsigned pk2(float a, float b) {
    __hip_bfloat162 h = __float22bfloat162_rn(float2{a, b});
    return *reinterpret_cast<unsigned*>(&h);
}

__device__ __forceinline__ bf16x8 load_b_frag(const float* __restrict__ W, int ldw,
                                              int kbase, int nbase, int lane) {
    int n  = nbase + (lane & 15);
    int k0 = kbase + ((lane >> 4) << 3);
    bf16x8 f;
#pragma unroll
    for (int e = 0; e < 8; ++e) f[e] = (short)f2bf(W[(k0 + e) * ldw + n]);
    return f;
}

__global__ __launch_bounds__(64) void prep_frags(
        const float* __restrict__ W0, const float* __restrict__ W1,
        const float* __restrict__ W2, ushort* __restrict__ ws) {
    const int b = blockIdx.x, lane = threadIdx.x;
    const int lr = lane & 15, kg = lane >> 4;
    const float* W; int ldw, n, k0;
    if (b < 56)      { W = W0; ldw = 224; n = (b >> 2) * 16 + lr; k0 = (b & 3) * 32 + (kg << 3); }
    else if (b < 64) { int t = b - 56; W = W1; ldw = 64; n = (t >> 1) * 16 + lr; k0 = (t & 1) * 32 + (kg << 3); }
    else             { W = W2; ldw = 32; n = (b - 64) * 16 + lr; k0 = (kg << 3); }
    bf16x8 f;
#pragma unroll
    for (int e = 0; e < 8; ++e) f[e] = (short)f2bf(W[(k0 + e) * ldw + n]);
    *reinterpret_cast<bf16x8*>(ws + (b * 64 + lane) * 8) = f;
}

// 2-wave blocks, 16 rows each: small convoy unit -> 8 staggered blocks/CU.
template <bool PRE>
__global__ __launch_bounds__(128, 4) void percep_kernel(
        const float* __restrict__ x,  const float* __restrict__ W0,
        const float* __restrict__ bias0, const float* __restrict__ W1,
        const float* __restrict__ W2, float* __restrict__ out,
        const ushort* __restrict__ ws) {
    __shared__ __align__(16) ushort xs[M_TILE * XSTR];   // 15616 B -> LDS allows 10 blocks/CU

    const int tid  = threadIdx.x;
    const int lane = tid & 63;
    const int w    = tid >> 6;      // wave = column-half of the S/V/T work
    const int lr   = lane & 15;
    const int kg   = lane >> 4;
    const int row0 = blockIdx.x * M_TILE;
    const bf16x8* F = reinterpret_cast<const bf16x8*>(ws);

    // ---------- stage 16 rows of x -> LDS bf16 (coalesced float4, packed cvt) ----------
    // x0: cols 0..127 straight ; x1[n,i,m]=x[n,128+3i+m] -> col 128+64m+i ;
    // x2[n,i,m]=x[n,320+5i+m] -> col 320+32m+i
#pragma unroll
    for (int it = 0; it < 4; ++it) {
        int idx = tid + it * 128;
        int row = idx >> 5, c4 = idx & 31;
        const float4 v = reinterpret_cast<const float4*>(x + (row0 + row) * DIN)[c4];
        uint2 o = { pk2(v.x, v.y), pk2(v.z, v.w) };
        *reinterpret_cast<uint2*>(&xs[row * XSTR + c4 * 4]) = o;
    }
#pragma unroll
    for (int it = 0; it < 2; ++it) {
        int idx = tid + it * 128;
        int row = idx >> 4, g = idx & 15;
        const float4* p = reinterpret_cast<const float4*>(x + (row0 + row) * DIN + 128 + 12 * g);
        float4 q0 = p[0], q1 = p[1], q2 = p[2];
        float v[12] = { q0.x, q0.y, q0.z, q0.w, q1.x, q1.y, q1.z, q1.w, q2.x, q2.y, q2.z, q2.w };
#pragma unroll
        for (int m = 0; m < 3; ++m) {
            uint2 o = { pk2(v[m], v[m + 3]), pk2(v[m + 6], v[m + 9]) };
            *reinterpret_cast<uint2*>(&xs[row * XSTR + 128 + 64 * m + 4 * g]) = o;
        }
    }
    {
        int row = tid >> 3, g = tid & 7;
        const float4* p = reinterpret_cast<const float4*>(x + (row0 + row) * DIN + 320 + 20 * g);
        float4 q0 = p[0], q1 = p[1], q2 = p[2], q3 = p[3], q4 = p[4];
        float v[20] = { q0.x, q0.y, q0.z, q0.w, q1.x, q1.y, q1.z, q1.w, q2.x, q2.y, q2.z, q2.w,
                        q3.x, q3.y, q3.z, q3.w, q4.x, q4.y, q4.z, q4.w };
#pragma unroll
        for (int m = 0; m < 5; ++m) {
            uint2 o = { pk2(v[m], v[m + 5]), pk2(v[m + 10], v[m + 15]) };
            *reinterpret_cast<uint2*>(&xs[row * XSTR + 320 + 32 * m + 4 * g]) = o;
        }
    }
    __syncthreads();   // the only barrier (2 waves)

    // ---------- A-frags for S ----------
    bf16x8 aS[4];
#pragma unroll
    for (int kk = 0; kk < 4; ++kk)
        aS[kk] = *reinterpret_cast<const bf16x8*>(&xs[lr * XSTR + kk * 32 + (kg << 3)]);

    const int orow = row0 + (kg << 2);   // first of this thread's 4 output rows

    auto s_acc = [&](int st) -> f32x4 {
        f32x4 acc = { 0.f, 0.f, 0.f, 0.f };
#pragma unroll
        for (int kk = 0; kk < 4; ++kk) {
            bf16x8 b = PRE ? F[(st * 4 + kk) * 64 + lane]
                           : load_b_frag(W0, 224, kk * 32, st * 16, lane);
            acc = __builtin_amdgcn_mfma_f32_16x16x32_bf16(aS[kk], b, acc, 0, 0, 0);
        }
        return acc;
    };
    auto gate_tile = [&](int st) -> f32x4 {
        f32x4 acc = s_acc(st);
        float bias = bias0[st * 16 + lr];
        f32x4 g;
#pragma unroll
        for (int r = 0; r < 4; ++r) {
            float s = acc[r] * INV_S128 + bias;
            g[r] = fmaxf(s, 0.f) * CST_RELU;
        }
        return g;
    };
    auto silu_tile = [&](int st) {
        f32x4 acc = s_acc(st);
        float bias = bias0[st * 16 + lr];
#pragma unroll
        for (int r = 0; r < 4; ++r) {
            float s = acc[r] * INV_S128 + bias;
            float val = CST_SILU * s * __builtin_amdgcn_rcpf(1.f + __expf(-s));
            out[(orow + r) * DOUT + st * 16 + lr] = val;
        }
    };

    // ---------- S phase: 3 gate tiles -> registers, 4 silu tiles -> out ----------
    // wave 0: gates 8,9,12 (V j0,j1; T j0), silu 0-3 ; wave 1: gates 10,11,13, silu 4-7
    f32x4 gV0 = gate_tile(w ? 10 : 8);
    f32x4 gV1 = gate_tile(w ? 11 : 9);
    f32x4 gT  = gate_tile(w ? 13 : 12);
    silu_tile(w * 4 + 0);
    silu_tile(w * 4 + 1);
    silu_tile(w * 4 + 2);
    silu_tile(w * 4 + 3);

    // ---------- V: 2 j-tiles (jtg = 2w, 2w+1) ----------
#pragma unroll
    for (int jt = 0; jt < 2; ++jt) {
        const int jtg = w * 2 + jt;
        f32x4 a0 = {0,0,0,0}, a1 = {0,0,0,0}, a2 = {0,0,0,0};
#pragma unroll
        for (int kk = 0; kk < 2; ++kk) {
            bf16x8 b = PRE ? F[(56 + jtg * 2 + kk) * 64 + lane]
                           : load_b_frag(W1, 64, kk * 32, jtg * 16, lane);
            const ushort* base = &xs[lr * XSTR + 128 + kk * 32 + (kg << 3)];
            a0 = __builtin_amdgcn_mfma_f32_16x16x32_bf16(*reinterpret_cast<const bf16x8*>(base +   0), b, a0, 0, 0, 0);
            a1 = __builtin_amdgcn_mfma_f32_16x16x32_bf16(*reinterpret_cast<const bf16x8*>(base +  64), b, a1, 0, 0, 0);
            a2 = __builtin_amdgcn_mfma_f32_16x16x32_bf16(*reinterpret_cast<const bf16x8*>(base + 128), b, a2, 0, 0, 0);
        }
        const f32x4& gv = jt ? gV1 : gV0;
        int j = jtg * 16 + lr;
#pragma unroll
        for (int r = 0; r < 4; ++r) {
            float gg = gv[r] * INV_S64;
            float* po = out + (orow + r) * DOUT + 128 + 3 * j;
            po[0] = a0[r] * gg; po[1] = a1[r] * gg; po[2] = a2[r] * gg;
        }
    }

    // ---------- T: 1 j-tile (tu = w), K=32 -> single MFMA per m ----------
    {
        bf16x8 bt = PRE ? F[(64 + w) * 64 + lane]
                        : load_b_frag(W2, 32, 0, w * 16, lane);
        const ushort* base = &xs[lr * XSTR + 320 + (kg << 3)];
        f32x4 z = {0,0,0,0};
        f32x4 a0 = __builtin_amdgcn_mfma_f32_16x16x32_bf16(*reinterpret_cast<const bf16x8*>(base +   0), bt, z, 0, 0, 0);
        f32x4 a1 = __builtin_amdgcn_mfma_f32_16x16x32_bf16(*reinterpret_cast<const bf16x8*>(base +  32), bt, z, 0, 0, 0);
        f32x4 a2 = __builtin_amdgcn_mfma_f32_16x16x32_bf16(*reinterpret_cast<const bf16x8*>(base +  64), bt, z, 0, 0, 0);
        f32x4 a3 = __builtin_amdgcn_mfma_f32_16x16x32_bf16(*reinterpret_cast<const bf16x8*>(base +  96), bt, z, 0, 0, 0);
        f32x4 a4 = __builtin_amdgcn_mfma_f32_16x16x32_bf16(*reinterpret_cast<const bf16x8*>(base + 128), bt, z, 0, 0, 0);
        int j = w * 16 + lr;
#pragma unroll
        for (int r = 0; r < 4; ++r) {
            float gg = gT[r] * INV_S32;
            float* po = out + (orow + r) * DOUT + 320 + 5 * j;
            po[0] = a0[r] * gg; po[1] = a1[r] * gg; po[2] = a2[r] * gg;
            po[3] = a3[r] * gg; po[4] = a4[r] * gg;
        }
    }
}

extern "C" void kernel_launch(void* const* d_in, const int* in_sizes, int n_in,
                              void* d_out, int out_size, void* d_ws, size_t ws_size,
                              hipStream_t stream) {
    const float* x  = (const float*)d_in[0];
    const float* W0 = (const float*)d_in[1];
    const float* b0 = (const float*)d_in[2];
    const float* W1 = (const float*)d_in[3];
    const float* W2 = (const float*)d_in[4];
    float* out = (float*)d_out;
    dim3 grid(NROWS / M_TILE), block(128);
    if (ws_size >= WS_BYTES) {
        hipLaunchKernelGGL(prep_frags, dim3(WS_FRAGS), dim3(64), 0, stream, W0, W1, W2, (ushort*)d_ws);
        hipLaunchKernelGGL((percep_kernel<true>), grid, block, 0, stream,
                           x, W0, b0, W1, W2, out, (const ushort*)d_ws);
    } else {
        hipLaunchKernelGGL((percep_kernel<false>), grid, block, 0, stream,
                           x, W0, b0, W1, W2, out, (const ushort*)d_ws);
    }
}